// Round 1
// baseline (172.442 us; speedup 1.0000x reference)
//
#include <hip/hip_runtime.h>
#include <math.h>

#define BATCH 8
#define SEQ 1024
#define DM 256
#define NH 8
#define DH 32
#define MTOT (BATCH*SEQ)
#define SCALING 5.656854249492381f

typedef __attribute__((ext_vector_type(8))) short short8;
typedef __attribute__((ext_vector_type(4))) float f32x4;
typedef _Float16 f16;
typedef __attribute__((ext_vector_type(8))) _Float16 f16x8;
typedef __attribute__((ext_vector_type(4))) _Float16 f16x4;

__device__ inline unsigned short f2bf(float f){
  union { float f; unsigned u; } x; x.f = f;
  unsigned r = x.u + 0x7fffu + ((x.u >> 16) & 1u);
  return (unsigned short)(r >> 16);
}
__device__ inline float bf2f(unsigned short s){
  union { unsigned u; float f; } x; x.u = ((unsigned)s) << 16;
  return x.f;
}

__device__ inline f32x4 mfma_bf16(short8 a, short8 b, f32x4 c){
  return __builtin_amdgcn_mfma_f32_16x16x32_bf16(a, b, c, 0, 0, 0);
}
__device__ inline f32x4 mfma_f16_32(f16x8 a, f16x8 b, f32x4 c){
  return __builtin_amdgcn_mfma_f32_16x16x32_f16(a, b, c, 0, 0, 0);
}
__device__ inline f32x4 mfma_f16_16(f16x4 a, f16x4 b, f32x4 c){
  return __builtin_amdgcn_mfma_f32_16x16x16f16(a, b, c, 0, 0, 0);
}

// ---- prep: X arrays -------------------------------------------------------
__global__ __launch_bounds__(256) void prep_x_kernel(
    const float* __restrict__ hs, const float* __restrict__ oq,
    unsigned short* __restrict__ xph, unsigned short* __restrict__ xpl,
    f16* __restrict__ xv){
  for (int i = blockIdx.x * blockDim.x + threadIdx.x; i < MTOT * DM;
       i += gridDim.x * blockDim.x){
    float h = hs[i];
    float p = h + oq[i];
    unsigned short hi = f2bf(p);
    xph[i] = hi;
    xpl[i] = f2bf(p - bf2f(hi));
    xv[i] = (f16)h;
  }
}

// ---- prep: weight arrays --------------------------------------------------
__global__ __launch_bounds__(256) void prep_w_kernel(
    const float* __restrict__ Wq, const float* __restrict__ Wk,
    const float* __restrict__ Wv, const float* __restrict__ Wo,
    unsigned short* __restrict__ wqh, unsigned short* __restrict__ wql,
    unsigned short* __restrict__ wkh, unsigned short* __restrict__ wkl,
    f16* __restrict__ wv16, f16* __restrict__ wo16){
  int i = blockIdx.x * blockDim.x + threadIdx.x;
  if (i < DM * DM){
    float q = Wq[i];
    unsigned short qh_ = f2bf(q);
    wqh[i] = qh_; wql[i] = f2bf(q - bf2f(qh_));
    float k = Wk[i];
    unsigned short kh_ = f2bf(k);
    wkh[i] = kh_; wkl[i] = f2bf(k - bf2f(kh_));
    wv16[i] = (f16)Wv[i];
    wo16[i] = (f16)Wo[i];
  }
}

// ---- fused QKV projection -------------------------------------------------
// C[m,n] = sum_k X[m,k] * W[n,k]  (W row-major [out][in] is already B^T layout)
// Q/K: split-bf16 (hi*hi + hi*lo + lo*hi).  V: fp16.
__global__ __launch_bounds__(256) void proj_qkv_kernel(
    const unsigned short* __restrict__ xph, const unsigned short* __restrict__ xpl,
    const f16* __restrict__ xv,
    const unsigned short* __restrict__ wqh, const unsigned short* __restrict__ wql,
    const unsigned short* __restrict__ wkh, const unsigned short* __restrict__ wkl,
    const f16* __restrict__ wv16,
    const float* __restrict__ bq, const float* __restrict__ bk, const float* __restrict__ bv,
    unsigned short* __restrict__ qh, unsigned short* __restrict__ ql,
    unsigned short* __restrict__ kh, unsigned short* __restrict__ kl,
    f16* __restrict__ vout){
  const int lane = threadIdx.x & 63;
  const int wave = threadIdx.x >> 6;
  const int m0 = (blockIdx.y * 4 + wave) * 16;
  const int n0 = blockIdx.x * 16;
  const int ar = (m0 + (lane & 15)) * DM + ((lane >> 4) * 8);
  const int br = (n0 + (lane & 15)) * DM + ((lane >> 4) * 8);
  f32x4 aq = {0.f, 0.f, 0.f, 0.f};
  f32x4 ak = {0.f, 0.f, 0.f, 0.f};
  f32x4 av = {0.f, 0.f, 0.f, 0.f};
  for (int kk = 0; kk < DM; kk += 32){
    short8 xh = *(const short8*)(xph + ar + kk);
    short8 xl = *(const short8*)(xpl + ar + kk);
    f16x8 xvv = *(const f16x8*)(xv + ar + kk);
    short8 qhw = *(const short8*)(wqh + br + kk);
    short8 qlw = *(const short8*)(wql + br + kk);
    short8 khw = *(const short8*)(wkh + br + kk);
    short8 klw = *(const short8*)(wkl + br + kk);
    f16x8 vw = *(const f16x8*)(wv16 + br + kk);
    aq = mfma_bf16(xh, qhw, aq);
    aq = mfma_bf16(xh, qlw, aq);
    aq = mfma_bf16(xl, qhw, aq);
    ak = mfma_bf16(xh, khw, ak);
    ak = mfma_bf16(xh, klw, ak);
    ak = mfma_bf16(xl, khw, ak);
    av = mfma_f16_32(xvv, vw, av);
  }
  const int col = n0 + (lane & 15);
  const float bqc = bq[col] * SCALING;
  const float bkc = bk[col];
  const float bvc = bv[col];
#pragma unroll
  for (int r = 0; r < 4; ++r){
    int row = m0 + (lane >> 4) * 4 + r;
    float qv = aq[r] * SCALING + bqc;
    unsigned short qhi = f2bf(qv);
    qh[row * DM + col] = qhi;
    ql[row * DM + col] = f2bf(qv - bf2f(qhi));
    float kv = ak[r] + bkc;
    unsigned short khi = f2bf(kv);
    kh[row * DM + col] = khi;
    kl[row * DM + col] = f2bf(kv - bf2f(khi));
    vout[row * DM + col] = (f16)(av[r] + bvc);
  }
}

// ---- flash attention ------------------------------------------------------
// Swapped QK^T: D = K_chunk * Q^T so lane holds P[q = lane&15][key = 4*(lane>>4)+r]
// which is exactly the B-fragment for the K=16 PV mfma. O accumulated transposed
// (O^T: col = q = lane&15) so softmax state stays lane-local.
__global__ __launch_bounds__(256) void attn_kernel(
    const unsigned short* __restrict__ qh, const unsigned short* __restrict__ ql,
    const unsigned short* __restrict__ kh, const unsigned short* __restrict__ kl,
    const f16* __restrict__ v, f16* __restrict__ aout){
  const int lane = threadIdx.x & 63;
  const int wave = threadIdx.x >> 6;
  const int bh = blockIdx.x >> 4;        // 0..63
  const int b = bh >> 3, h = bh & 7;
  const int q0 = ((blockIdx.x & 15) * 4 + wave) * 16;
  const int rowbase = b * SEQ;
  const int col0 = h * DH;
  const int dh0 = (lane >> 4) * 8;
  const int qrow = rowbase + q0 + (lane & 15);
  short8 bqh = *(const short8*)(qh + qrow * DM + col0 + dh0);
  short8 bql = *(const short8*)(ql + qrow * DM + col0 + dh0);
  float m = -INFINITY, lsum = 0.f;
  f32x4 o0 = {0.f, 0.f, 0.f, 0.f};
  f32x4 o1 = {0.f, 0.f, 0.f, 0.f};
  const int vc = col0 + (lane & 15);
  for (int c = 0; c < SEQ; c += 16){
    const int krow = rowbase + c + (lane & 15);
    short8 akh = *(const short8*)(kh + krow * DM + col0 + dh0);
    short8 akl = *(const short8*)(kl + krow * DM + col0 + dh0);
    f32x4 s = {0.f, 0.f, 0.f, 0.f};
    s = mfma_bf16(akh, bqh, s);
    s = mfma_bf16(akh, bql, s);
    s = mfma_bf16(akl, bqh, s);
    float cmax = fmaxf(fmaxf(s[0], s[1]), fmaxf(s[2], s[3]));
    cmax = fmaxf(cmax, __shfl_xor(cmax, 16, 64));
    cmax = fmaxf(cmax, __shfl_xor(cmax, 32, 64));
    const float mnew = fmaxf(m, cmax);
    const float scale = expf(m - mnew);
    float p0 = expf(s[0] - mnew);
    float p1 = expf(s[1] - mnew);
    float p2 = expf(s[2] - mnew);
    float p3 = expf(s[3] - mnew);
    float ps = p0 + p1 + p2 + p3;
    ps += __shfl_xor(ps, 16, 64);
    ps += __shfl_xor(ps, 32, 64);
    lsum = lsum * scale + ps;
    m = mnew;
    o0[0] *= scale; o0[1] *= scale; o0[2] *= scale; o0[3] *= scale;
    o1[0] *= scale; o1[1] *= scale; o1[2] *= scale; o1[3] *= scale;
    f16x4 bp = {(f16)p0, (f16)p1, (f16)p2, (f16)p3};
    const int kj = rowbase + c + (lane >> 4) * 4;
    f16x4 av0, av1;
#pragma unroll
    for (int j = 0; j < 4; ++j){
      av0[j] = v[(kj + j) * DM + vc];
      av1[j] = v[(kj + j) * DM + vc + 16];
    }
    o0 = mfma_f16_16(av0, bp, o0);
    o1 = mfma_f16_16(av1, bp, o1);
  }
  const float inv = 1.f / lsum;
  const int orow = (rowbase + q0 + (lane & 15)) * DM + col0;
#pragma unroll
  for (int r = 0; r < 4; ++r){
    const int dh = (lane >> 4) * 4 + r;
    aout[orow + dh] = (f16)(o0[r] * inv);
    aout[orow + 16 + dh] = (f16)(o1[r] * inv);
  }
}

// ---- output projection ----------------------------------------------------
__global__ __launch_bounds__(256) void oproj_kernel(
    const f16* __restrict__ attn, const f16* __restrict__ wo16,
    const float* __restrict__ bo, float* __restrict__ out){
  const int lane = threadIdx.x & 63;
  const int wave = threadIdx.x >> 6;
  const int m0 = (blockIdx.y * 4 + wave) * 16;
  const int n0 = blockIdx.x * 16;
  const int ar = (m0 + (lane & 15)) * DM + ((lane >> 4) * 8);
  const int br = (n0 + (lane & 15)) * DM + ((lane >> 4) * 8);
  f32x4 acc = {0.f, 0.f, 0.f, 0.f};
  for (int kk = 0; kk < DM; kk += 32){
    f16x8 a = *(const f16x8*)(attn + ar + kk);
    f16x8 w = *(const f16x8*)(wo16 + br + kk);
    acc = mfma_f16_32(a, w, acc);
  }
  const int col = n0 + (lane & 15);
  const float bc = bo[col];
#pragma unroll
  for (int r = 0; r < 4; ++r){
    int row = m0 + (lane >> 4) * 4 + r;
    out[row * DM + col] = acc[r] + bc;
  }
}

extern "C" void kernel_launch(void* const* d_in, const int* in_sizes, int n_in,
                              void* d_out, int out_size, void* d_ws, size_t ws_size,
                              hipStream_t stream){
  const float* hs = (const float*)d_in[0];
  const float* oq = (const float*)d_in[1];
  const float* Wq = (const float*)d_in[2];
  const float* bq = (const float*)d_in[3];
  const float* Wk = (const float*)d_in[4];
  const float* bk = (const float*)d_in[5];
  const float* Wv = (const float*)d_in[6];
  const float* bv = (const float*)d_in[7];
  const float* Wo = (const float*)d_in[8];
  const float* bo = (const float*)d_in[9];
  float* out = (float*)d_out;

  char* p = (char*)d_ws;
  auto alloc = [&](size_t bytes) -> char* {
    char* r = p;
    p += (bytes + 255) & ~((size_t)255);
    return r;
  };
  const size_t xb = (size_t)MTOT * DM * 2;  // 4 MiB per bf16/f16 plane
  unsigned short* xph = (unsigned short*)alloc(xb);
  unsigned short* xpl = (unsigned short*)alloc(xb);
  f16* xv = (f16*)alloc(xb);
  unsigned short* qh = (unsigned short*)alloc(xb);
  unsigned short* ql = (unsigned short*)alloc(xb);
  unsigned short* kh = (unsigned short*)alloc(xb);
  unsigned short* kl = (unsigned short*)alloc(xb);
  f16* vv = (f16*)alloc(xb);
  f16* attn = (f16*)alloc(xb);
  const size_t wb = (size_t)DM * DM * 2;  // 128 KiB per weight plane
  unsigned short* wqh = (unsigned short*)alloc(wb);
  unsigned short* wql = (unsigned short*)alloc(wb);
  unsigned short* wkh = (unsigned short*)alloc(wb);
  unsigned short* wkl = (unsigned short*)alloc(wb);
  f16* wv16 = (f16*)alloc(wb);
  f16* wo16 = (f16*)alloc(wb);

  hipLaunchKernelGGL(prep_x_kernel, dim3(1024), dim3(256), 0, stream,
                     hs, oq, xph, xpl, xv);
  hipLaunchKernelGGL(prep_w_kernel, dim3(DM * DM / 256), dim3(256), 0, stream,
                     Wq, Wk, Wv, Wo, wqh, wql, wkh, wkl, wv16, wo16);
  hipLaunchKernelGGL(proj_qkv_kernel, dim3(16, 128), dim3(256), 0, stream,
                     xph, xpl, xv, wqh, wql, wkh, wkl, wv16, bq, bk, bv,
                     qh, ql, kh, kl, vv);
  hipLaunchKernelGGL(attn_kernel, dim3(1024), dim3(256), 0, stream,
                     qh, ql, kh, kl, vv, attn);
  hipLaunchKernelGGL(oproj_kernel, dim3(16, 128), dim3(256), 0, stream,
                     attn, wo16, bo, out);
}